// Round 9
// baseline (1821.527 us; speedup 1.0000x reference)
//
#include <hip/hip_runtime.h>
#include <math.h>

#define PI_F 3.14159265358979323846f

typedef _Float16 half8 __attribute__((ext_vector_type(8)));
typedef _Float16 half4 __attribute__((ext_vector_type(4)));
typedef float f32x4 __attribute__((ext_vector_type(4)));

#define MFMA(a, b, c) __builtin_amdgcn_mfma_f32_16x16x32_f16(a, b, c, 0, 0, 0)
#define OFF_CAT 49152   // halfs: wcat starts after whh0 (3*128*128)

__device__ __forceinline__ float rcp_fast(float x) { return __builtin_amdgcn_rcpf(x); }
__device__ __forceinline__ float sigmoid_f(float x) {
    float e = __expf(-x);
    return rcp_fast(1.0f + e);
}
__device__ __forceinline__ float tanh_f(float x) {
    float ax = fabsf(x);
    float e  = __expf(-2.0f * ax);
    float t  = (1.0f - e) * rcp_fast(1.0f + e);
    return x >= 0.0f ? t : -t;
}

// Prep: f16 weights; concat [w_ih1|w_hh1] along K for layer 1.
__global__ void prep_kernel(const float* __restrict__ whh0,
                            const float* __restrict__ wih1,
                            const float* __restrict__ whh1,
                            _Float16* __restrict__ wsp) {
    int i = blockIdx.x * 256 + threadIdx.x;
    if (i < 49152) wsp[i] = (_Float16)whh0[i];
    if (i < 98304) {
        int n = i >> 8, k = i & 255;
        float v = (k < 128) ? wih1[(n << 7) + k] : whh1[(n << 7) + k - 128];
        wsp[OFF_CAT + i] = (_Float16)v;
    }
}

// 512 threads (8 waves), 64 elems/block, 1 block/CU, 2 waves/SIMD, 256 regs.
// Each wave owns 16 dims of BOTH layers; weights register-resident (144 VGPR,
// pinned); h state hi-only in LDS with per-lane lo corrections in registers
// (round-8 scheme: halves MFMA + LDS-h, exact recurrence).
//
// NEW (this round): ONE barrier per tick via the fused epoch (round-7 parity
// scheme, proven correct at full precision):
//     { B(t-1);  A(t);  head(t-2) }  |barrier|
// Rationale from round-8 counters: wall 15.5K cyc/tick ~= MFMA 5.3K + VALU
// 6.2K + LDS ~5.5K with pipes ADDITIVE -- 2-barrier lockstep serializes the
// read/MFMA/epilogue bursts. The fused window has all 144 MFMA + both
// epilogues + head with no intra-window sync: B's kc4-7 chains overlap A's
// epilogue VALU; waves drift within the window. Shared kc0-3 fragments (A and
// B(t-1) both read h0[pB]) cut LDS b128 reads 48 -> 32/wave/tick.
//
// Parity audit (epoch tick): A reads h0[pB] (+own-dim hph), writes h0[pA];
// B reads h0[pB] (kc0-3) + h1[pA] (kc4-7 and hph), writes h1[pB]; head(t-2)
// reads h1[pA]. Same-array epoch accesses are read-read or opposite-parity;
// producers ran in earlier epochs across the barrier. Gate operands AND
// accumulation order identical to round-8 (kc ascending; head reads the same
// h1(s) values two ticks later) -> output bit-identical.
//
// h planes (64 elems) in MFMA-B-frag chunk order, double-buffered by parity:
//   plane[buf][(kc*4 + eb)*512 + (qd*16 + l4)*8 + j] = h[e=eb*16+l4][dim=32kc+8qd+j]

__global__ void __launch_bounds__(512, 2) rnn_wf_pipe(
    const int*   __restrict__ x,
    const float* __restrict__ w_ih0,
    const float* __restrict__ w_lin,
    const float* __restrict__ b_lin,
    const _Float16* __restrict__ wsp,
    float*       __restrict__ out,
    int nbatch)
{
    __shared__ _Float16 h0[2][8192], h1[2][8192];
    __shared__ float gi0T[2][3][128];          // [prev-bit][gate][dim]
    __shared__ float wlinT[256];               // w_lin flat
    __shared__ unsigned long long bmk[64];     // per-element bit mask

    const int t    = threadIdx.x;
    const int wv   = t >> 6;                   // 0..7 = dim-block (16 dims)
    const int l4   = t & 15;
    const int q    = (t >> 4) & 3;
    const int ebg  = blockIdx.x * 64;

    // ---- init LDS ----
    for (int i = t; i < 8192; i += 512) {      // 8192 ints = 2 bufs x 8192 halfs per array
        ((int*)h0)[i] = 0; ((int*)h1)[i] = 0;
    }
    for (int i = t; i < 768; i += 512) {
        int b = i / 384, rem = i - b * 384;
        ((float*)gi0T)[b * 384 + rem] = w_ih0[rem * 2 + b];
    }
    if (t < 256) wlinT[t] = w_lin[t];
    if (t < 256) {   // bit masks: thread t -> element t>>2, quarter t&3
        int el = t >> 2, qq = t & 3;
        int eg = ebg + el; if (eg >= nbatch) eg = nbatch - 1;
        const int* xr = x + (size_t)eg * 64 + qq * 16;
        unsigned long long m = 0ull;
#pragma unroll
        for (int i = 0; i < 16; ++i)
            m |= ((unsigned long long)((unsigned)(xr[i] + 1) >> 1)) << (qq * 16 + i);
        m |= __shfl_xor(m, 1);
        m |= __shfl_xor(m, 2);
        if (qq == 0) bmk[el] = m;
    }

    const int lo8 = ((q << 4) + l4) << 3;      // = lane*8 halfs: B-frag chunk offset
    const int d0  = wv * 16 + 4 * q;           // first of 4 dims this lane updates
    const int epb = (d0 >> 5) * 2048 + ((d0 >> 3) & 3) * 128 + l4 * 8 + (d0 & 7);

    // ---- register-resident weights ----
    half8 w0[3][4];                            // 48 VGPR
#pragma unroll
    for (int g = 0; g < 3; ++g)
#pragma unroll
        for (int kc = 0; kc < 4; ++kc)
            w0[g][kc] = *(const half8*)(wsp + (size_t)(g * 128 + 16 * wv + l4) * 128 + 32 * kc + 8 * q);
    half8 w1[3][8];                            // 96 VGPR
#pragma unroll
    for (int g = 0; g < 3; ++g)
#pragma unroll
        for (int kc = 0; kc < 8; ++kc)
            w1[g][kc] = *(const half8*)(wsp + OFF_CAT + (size_t)(g * 128 + 16 * wv + l4) * 256 + 32 * kc + 8 * q);

    // ---- register-resident lo-state (per-lane own dims, per eb) ----
    half4 l0s[4], l1s[4];
#pragma unroll
    for (int eb = 0; eb < 4; ++eb) {
        l0s[eb] = (half4){0, 0, 0, 0};
        l1s[eb] = (half4){0, 0, 0, 0};
    }

    // head state (waves 0-3, q-replicated)
    float amp = 1.0f, phs = 0.0f, nu = 0.0f, nd = 0.0f;
    float bl0 = 0.0f, bl1 = 0.0f;
    const int eh = (wv << 4) + l4;
    if (wv < 4) { bl0 = b_lin[0]; bl1 = b_lin[1]; }

    __syncthreads();

    for (int tick = 0; tick <= 65; ++tick) {
        const int pA = tick & 1;               // A writes h0[pA]; B/head read h1[pA]
        const int pB = pA ^ 1;                 // A+B read h0[pB]; B writes h1[pB]
        const bool doA = tick < 64;            // A(tick)
        const bool doB = (tick >= 1) && (tick < 65);   // B(tick-1)

        // pin weights: opaque loop-carried registers (no remat from memory)
#pragma unroll
        for (int g = 0; g < 3; ++g) {
#pragma unroll
            for (int kc = 0; kc < 4; ++kc) asm volatile("" : "+v"(w0[g][kc]));
#pragma unroll
            for (int kc = 0; kc < 8; ++kc) asm volatile("" : "+v"(w1[g][kc]));
        }

        if (doA || doB) {
#pragma unroll
            for (int eb = 0; eb < 4; ++eb) {
                f32x4 a0R = {0,0,0,0}, a0Z = {0,0,0,0}, a0N = {0,0,0,0};
                f32x4 a1R = {0,0,0,0}, a1Z = {0,0,0,0};
                f32x4 a1Ni = {0,0,0,0}, a1Nh = {0,0,0,0};

                // kc 0-3: SHARED h0[pB] fragments feed both layers' MFMAs
#pragma unroll
                for (int kc = 0; kc < 4; ++kc) {
                    const int cb = (kc * 4 + eb) * 512 + lo8;
                    half8 hh = *(const half8*)&h0[pB][cb];
                    if (doB) {
                        a1R  = MFMA(w1[0][kc], hh, a1R);
                        a1Z  = MFMA(w1[1][kc], hh, a1Z);
                        a1Ni = MFMA(w1[2][kc], hh, a1Ni);
                    }
                    if (doA) {
                        a0R = MFMA(w0[0][kc], hh, a0R);
                        a0Z = MFMA(w0[1][kc], hh, a0Z);
                        a0N = MFMA(w0[2][kc], hh, a0N);
                    }
                }

                if (doB) {
                    // kc 4-7: h1(tick-2) operand from h1[pA]
#pragma unroll
                    for (int kc = 4; kc < 8; ++kc) {
                        const int cb = ((kc & 3) * 4 + eb) * 512 + lo8;
                        half8 hh = *(const half8*)&h1[pA][cb];
                        a1R  = MFMA(w1[0][kc], hh, a1R);
                        a1Z  = MFMA(w1[1][kc], hh, a1Z);
                        a1Nh = MFMA(w1[2][kc], hh, a1Nh);
                    }
                    // B epilogue: hprev = hi(h1[pA]) + lo(reg); write h1[pB]
                    const int ep_ = epb + eb * 512;
                    half4 hph = *(const half4*)&h1[pA][ep_];
                    half4 hpl = l1s[eb];
                    half4 nh, nl;
#pragma unroll
                    for (int r = 0; r < 4; ++r) {
                        float rr = sigmoid_f(a1R[r]);
                        float zz = sigmoid_f(a1Z[r]);
                        float nn = tanh_f(a1Ni[r] + rr * a1Nh[r]);
                        float hprev = (float)hph[r] + (float)hpl[r];
                        float hn = (1.0f - zz) * nn + zz * hprev;
                        _Float16 hi = (_Float16)hn;
                        nh[r] = hi;
                        nl[r] = (_Float16)(hn - (float)hi);
                    }
                    *(half4*)&h1[pB][ep_] = nh;
                    l1s[eb] = nl;
                }

                if (doA) {
                    // A epilogue: gi from bit(tick-1); hprev = hi(h0[pB]) +
                    // lo(reg); write h0[pA]
                    const int e = eb * 16 + l4;
                    f32x4 giR = {0,0,0,0}, giZ = {0,0,0,0}, giN = {0,0,0,0};
                    if (tick > 0) {
                        int pb = (int)((bmk[e] >> (tick - 1)) & 1ull);
                        const float* gp = &gi0T[pb][0][0];
                        giR = *(const f32x4*)(gp + d0);
                        giZ = *(const f32x4*)(gp + 128 + d0);
                        giN = *(const f32x4*)(gp + 256 + d0);
                    }
                    const int ep_ = epb + eb * 512;
                    half4 hph = *(const half4*)&h0[pB][ep_];
                    half4 hpl = l0s[eb];
                    half4 nh, nl;
#pragma unroll
                    for (int r = 0; r < 4; ++r) {
                        float rr = sigmoid_f(giR[r] + a0R[r]);
                        float zz = sigmoid_f(giZ[r] + a0Z[r]);
                        float nn = tanh_f(giN[r] + rr * a0N[r]);
                        float hprev = (float)hph[r] + (float)hpl[r];
                        float hn = (1.0f - zz) * nn + zz * hprev;
                        _Float16 hi = (_Float16)hn;
                        nh[r] = hi;
                        nl[r] = (_Float16)(hn - (float)hi);
                    }
                    *(half4*)&h0[pA][ep_] = nh;
                    l0s[eb] = nl;
                }
            }
        }

        // ---- head for step s = tick-2; h1(s) parity s&1 == pA (B writes
        //      h1[pB] this epoch -> disjoint). Lane-linear, conflict-free. ----
        if (wv < 4 && tick >= 2) {
            const int s = tick - 2;
            float l0 = 0.0f, l1 = 0.0f;
#pragma unroll
            for (int ks = 0; ks < 4; ++ks) {
                const int cb = (ks * 4 + wv) * 512 + lo8;
                half8 hh = *(const half8*)&h1[pA][cb];
                const float* wpl = &wlinT[32 * ks + 8 * q];
#pragma unroll
                for (int j = 0; j < 8; ++j) {
                    float hv = (float)hh[j];
                    l0 = fmaf(hv, wpl[j], l0);
                    l1 = fmaf(hv, wpl[128 + j], l1);
                }
            }
            l0 += __shfl_xor(l0, 16); l0 += __shfl_xor(l0, 32); l0 += bl0;
            l1 += __shfl_xor(l1, 16); l1 += __shfl_xor(l1, 32); l1 += bl1;

            float p0 = sigmoid_f(l0 - l1);
            float p1 = sigmoid_f(l1 - l0);
            float y0 = sqrtf(p0), y1 = sqrtf(p1);
            float ph0 = PI_F * l0 * rcp_fast(1.0f + fabsf(l0));
            float ph1 = PI_F * l1 * rcp_fast(1.0f + fabsf(l1));

            int bit = (int)((bmk[eh] >> s) & 1ull);
            bool is_even = (s & 1) == 0;
            float num   = is_even ? nu : nd;
            float lower = -16.0f + (float)(s >> 1);
            float occ   = (num < 16.0f) ? 1.0f : 0.0f;
            float unocc = (num > lower) ? 1.0f : 0.0f;
            if (s >= 16) {
                float m0 = y0 * unocc, m1 = y1 * occ;
                float nrm = fmaxf(sqrtf(m0 * m0 + m1 * m1), 1e-12f);
                float rn  = rcp_fast(nrm);
                y0 = m0 * rn; y1 = m1 * rn;
            }
            if (is_even) nu += (float)bit; else nd += (float)bit;
            amp *= bit ? y1 : y0;
            phs += bit ? ph1 : ph0;
        }

        __syncthreads();
    }

    if (wv < 4 && q == 0) {
        int eg = ebg + eh;
        if (eg < nbatch) {
            float s, c;
            sincosf(phs, &s, &c);
            out[eg]          = amp * c;
            out[nbatch + eg] = amp * s;
        }
    }
}

extern "C" void kernel_launch(void* const* d_in, const int* in_sizes, int n_in,
                              void* d_out, int out_size, void* d_ws, size_t ws_size,
                              hipStream_t stream) {
    const int*   x     = (const int*)  d_in[0];
    const float* w_ih0 = (const float*)d_in[1];
    const float* w_hh0 = (const float*)d_in[2];
    const float* w_ih1 = (const float*)d_in[3];
    const float* w_hh1 = (const float*)d_in[4];
    const float* w_lin = (const float*)d_in[5];
    const float* b_lin = (const float*)d_in[6];
    float* out = (float*)d_out;
    _Float16* wsp = (_Float16*)d_ws;

    const int nbatch = in_sizes[0] / 64;

    prep_kernel<<<384, 256, 0, stream>>>(w_hh0, w_ih1, w_hh1, wsp);

    const int blocks = (nbatch + 63) / 64;
    rnn_wf_pipe<<<blocks, 512, 0, stream>>>(x, w_ih0, w_lin, b_lin, wsp, out, nbatch);
}

// Round 10
// 1810.096 us; speedup vs baseline: 1.0063x; 1.0063x over previous
//
#include <hip/hip_runtime.h>
#include <math.h>

#define PI_F 3.14159265358979323846f

typedef _Float16 half8 __attribute__((ext_vector_type(8)));
typedef _Float16 half4 __attribute__((ext_vector_type(4)));
typedef float f32x4 __attribute__((ext_vector_type(4)));

#define MFMA(a, b, c) __builtin_amdgcn_mfma_f32_16x16x32_f16(a, b, c, 0, 0, 0)
#define OFF_CAT 49152   // halfs: wcat starts after whh0 (3*128*128)

__device__ __forceinline__ float rcp_fast(float x) { return __builtin_amdgcn_rcpf(x); }
__device__ __forceinline__ float sigmoid_f(float x) {
    float e = __expf(-x);
    return rcp_fast(1.0f + e);
}
__device__ __forceinline__ float tanh_f(float x) {
    float ax = fabsf(x);
    float e  = __expf(-2.0f * ax);
    float t  = (1.0f - e) * rcp_fast(1.0f + e);
    return x >= 0.0f ? t : -t;
}

// Prep: f16 weights; concat [w_ih1|w_hh1] along K for layer 1.
__global__ void prep_kernel(const float* __restrict__ whh0,
                            const float* __restrict__ wih1,
                            const float* __restrict__ whh1,
                            _Float16* __restrict__ wsp) {
    int i = blockIdx.x * 256 + threadIdx.x;
    if (i < 49152) wsp[i] = (_Float16)whh0[i];
    if (i < 98304) {
        int n = i >> 8, k = i & 255;
        float v = (k < 128) ? wih1[(n << 7) + k] : whh1[(n << 7) + k - 128];
        wsp[OFF_CAT + i] = (_Float16)v;
    }
}

// 512 threads (8 waves), 64 elems/block, 1 block/CU, 2 waves/SIMD, 256 regs.
// Round-8 structure (best verified, 1654us): each wave owns 16 dims of BOTH
// layers; h state hi-only through LDS/MFMA; 2 barriers/tick
//     { A: h0(t) | bar | B: h1(t) | bar | head(t) || A(t+1) }
// Barrier-fusion is now triple-falsified (r3, r7, r9) -- sync structure fixed.
//
// Round-9 diagnosis: MfmaUtil + VALUBusy ~= 95-101% across r5/r8/r9 -- the
// SIMD issue port is SATURATED; the lever is instruction count. Two cuts:
//
// 1. Weight pins "+a" (AGPR) instead of "+v". MFMA reads A-operands from
//    AGPRs directly (gfx950 unified file); weights are only consumed by MFMA
//    -> zero transfer cost. Previously the 144 "+v"-pinned weight regs filled
//    the arch file and pushed accumulators into AGPRs, costing ~220
//    v_accvgpr_write/read transfer instructions per wave-tick.
// 2. Own-dim h state in f32 REGISTERS (f32x4 h0s/h1s[4], statically indexed):
//    replaces the hi(LDS)+lo(reg) pair -- kills hph ds_reads, 8 cvt + adds
//    per eb, and the lo sub+cvt chain (~130 VALU + 8 DS per wave-tick).
//    Recurrence becomes exactly f32 (strictly more precise than hi+lo).
//
// Gate pre-activations bit-identical to round-8 (same MFMA operands + order);
// hprev differs at the 2^-22 level -> output shifts ~ulp, well within tol.
//
// h planes (64 elems) in MFMA-B-frag chunk order, double-buffered by parity:
//   plane[buf][(kc*4 + eb)*512 + (qd*16 + l4)*8 + j] = h[e=eb*16+l4][dim=32kc+8qd+j]

__global__ void __launch_bounds__(512, 2) rnn_wf_pipe(
    const int*   __restrict__ x,
    const float* __restrict__ w_ih0,
    const float* __restrict__ w_lin,
    const float* __restrict__ b_lin,
    const _Float16* __restrict__ wsp,
    float*       __restrict__ out,
    int nbatch)
{
    __shared__ _Float16 h0[2][8192], h1[2][8192];
    __shared__ float gi0T[2][3][128];          // [prev-bit][gate][dim]
    __shared__ float wlinT[256];               // w_lin flat
    __shared__ unsigned long long bmk[64];     // per-element bit mask

    const int t    = threadIdx.x;
    const int wv   = t >> 6;                   // 0..7 = dim-block (16 dims)
    const int l4   = t & 15;
    const int q    = (t >> 4) & 3;
    const int ebg  = blockIdx.x * 64;

    // ---- init LDS ----
    for (int i = t; i < 8192; i += 512) {      // 8192 ints = 2 bufs x 8192 halfs per array
        ((int*)h0)[i] = 0; ((int*)h1)[i] = 0;
    }
    for (int i = t; i < 768; i += 512) {
        int b = i / 384, rem = i - b * 384;
        ((float*)gi0T)[b * 384 + rem] = w_ih0[rem * 2 + b];
    }
    if (t < 256) wlinT[t] = w_lin[t];
    if (t < 256) {   // bit masks: thread t -> element t>>2, quarter t&3
        int el = t >> 2, qq = t & 3;
        int eg = ebg + el; if (eg >= nbatch) eg = nbatch - 1;
        const int* xr = x + (size_t)eg * 64 + qq * 16;
        unsigned long long m = 0ull;
#pragma unroll
        for (int i = 0; i < 16; ++i)
            m |= ((unsigned long long)((unsigned)(xr[i] + 1) >> 1)) << (qq * 16 + i);
        m |= __shfl_xor(m, 1);
        m |= __shfl_xor(m, 2);
        if (qq == 0) bmk[el] = m;
    }

    const int lo8 = ((q << 4) + l4) << 3;      // = lane*8 halfs: B-frag chunk offset
    const int d0  = wv * 16 + 4 * q;           // first of 4 dims this lane updates
    const int epb = (d0 >> 5) * 2048 + ((d0 >> 3) & 3) * 128 + l4 * 8 + (d0 & 7);

    // ---- register-resident weights (pinned to AGPRs in the tick loop) ----
    half8 w0[3][4];                            // 48 regs
#pragma unroll
    for (int g = 0; g < 3; ++g)
#pragma unroll
        for (int kc = 0; kc < 4; ++kc)
            w0[g][kc] = *(const half8*)(wsp + (size_t)(g * 128 + 16 * wv + l4) * 128 + 32 * kc + 8 * q);
    half8 w1[3][8];                            // 96 regs
#pragma unroll
    for (int g = 0; g < 3; ++g)
#pragma unroll
        for (int kc = 0; kc < 8; ++kc)
            w1[g][kc] = *(const half8*)(wsp + OFF_CAT + (size_t)(g * 128 + 16 * wv + l4) * 256 + 32 * kc + 8 * q);

    // ---- own-dim h state in f32 registers (statically indexed) ----
    f32x4 h0s[4], h1s[4];
#pragma unroll
    for (int eb = 0; eb < 4; ++eb) {
        h0s[eb] = (f32x4){0.f, 0.f, 0.f, 0.f};
        h1s[eb] = (f32x4){0.f, 0.f, 0.f, 0.f};
    }

    // head state (waves 0-3, q-replicated)
    float amp = 1.0f, phs = 0.0f, nu = 0.0f, nd = 0.0f;
    float bl0 = 0.0f, bl1 = 0.0f;
    const int eh = (wv << 4) + l4;
    if (wv < 4) { bl0 = b_lin[0]; bl1 = b_lin[1]; }

    __syncthreads();

    for (int tick = 0; tick < 64; ++tick) {
        const int cur = tick & 1, prv = cur ^ 1;

        // pin weights into AGPRs: opaque loop-carried registers; MFMA reads
        // A-operands from AGPRs directly -> no transfers, arch file free for acc
#pragma unroll
        for (int g = 0; g < 3; ++g) {
#pragma unroll
            for (int kc = 0; kc < 4; ++kc) asm volatile("" : "+a"(w0[g][kc]));
#pragma unroll
            for (int kc = 0; kc < 8; ++kc) asm volatile("" : "+a"(w1[g][kc]));
        }

        // ---- Phase A: h0(tick) = GRU0(onehot(bit(tick-1)), h0(tick-1)) ----
#pragma unroll
        for (int eb = 0; eb < 4; ++eb) {
            f32x4 aR = {0,0,0,0}, aZ = {0,0,0,0}, aN = {0,0,0,0};
#pragma unroll
            for (int kc = 0; kc < 4; ++kc) {
                const int cb = (kc * 4 + eb) * 512 + lo8;
                half8 hh = *(const half8*)&h0[prv][cb];
                aR = MFMA(w0[0][kc], hh, aR);
                aZ = MFMA(w0[1][kc], hh, aZ);
                aN = MFMA(w0[2][kc], hh, aN);
            }
            const int e = eb * 16 + l4;
            f32x4 giR = {0,0,0,0}, giZ = {0,0,0,0}, giN = {0,0,0,0};
            if (tick > 0) {
                int pb = (int)((bmk[e] >> (tick - 1)) & 1ull);
                const float* gp = &gi0T[pb][0][0];
                giR = *(const f32x4*)(gp + d0);
                giZ = *(const f32x4*)(gp + 128 + d0);
                giN = *(const f32x4*)(gp + 256 + d0);
            }
            const int ep_ = epb + eb * 512;
            f32x4 hp = h0s[eb];
            f32x4 hnv;
            half4 nh;
#pragma unroll
            for (int r = 0; r < 4; ++r) {
                float rr = sigmoid_f(giR[r] + aR[r]);
                float zz = sigmoid_f(giZ[r] + aZ[r]);
                float nn = tanh_f(giN[r] + rr * aN[r]);
                float hn = (1.0f - zz) * nn + zz * hp[r];
                hnv[r] = hn;
                nh[r] = (_Float16)hn;
            }
            h0s[eb] = hnv;
            *(half4*)&h0[cur][ep_] = nh;
        }

        __syncthreads();

        // ---- Phase B: h1(tick) = GRU1(h0(tick), h1(tick-1)) ----
#pragma unroll
        for (int eb = 0; eb < 4; ++eb) {
            f32x4 aR = {0,0,0,0}, aZ = {0,0,0,0};
            f32x4 aNi = {0,0,0,0}, aNh = {0,0,0,0};
#pragma unroll
            for (int kc = 0; kc < 8; ++kc) {
                const int cb = ((kc & 3) * 4 + eb) * 512 + lo8;
                half8 hh;
                if (kc < 4) hh = *(const half8*)&h0[cur][cb];
                else        hh = *(const half8*)&h1[prv][cb];
                aR = MFMA(w1[0][kc], hh, aR);
                aZ = MFMA(w1[1][kc], hh, aZ);
                if (kc < 4) aNi = MFMA(w1[2][kc], hh, aNi);
                else        aNh = MFMA(w1[2][kc], hh, aNh);
            }
            const int ep_ = epb + eb * 512;
            f32x4 hp = h1s[eb];
            f32x4 hnv;
            half4 nh;
#pragma unroll
            for (int r = 0; r < 4; ++r) {
                float rr = sigmoid_f(aR[r]);
                float zz = sigmoid_f(aZ[r]);
                float nn = tanh_f(aNi[r] + rr * aNh[r]);
                float hn = (1.0f - zz) * nn + zz * hp[r];
                hnv[r] = hn;
                nh[r] = (_Float16)hn;
            }
            h1s[eb] = hnv;
            *(half4*)&h1[cur][ep_] = nh;
        }

        __syncthreads();

        // ---- head for step s = tick; h1(s) in buf cur.  Waves 0-3 only;
        //      waves 4-7 proceed straight into A(tick+1) (disjoint arrays).
        //      Lane-linear reads (conflict-free); xor-16/32 reduce. ----
        if (wv < 4) {
            const int s = tick;
            float l0 = 0.0f, l1 = 0.0f;
#pragma unroll
            for (int ks = 0; ks < 4; ++ks) {
                const int cb = (ks * 4 + wv) * 512 + lo8;
                half8 hh = *(const half8*)&h1[cur][cb];
                const float* wpl = &wlinT[32 * ks + 8 * q];
#pragma unroll
                for (int j = 0; j < 8; ++j) {
                    float hv = (float)hh[j];
                    l0 = fmaf(hv, wpl[j], l0);
                    l1 = fmaf(hv, wpl[128 + j], l1);
                }
            }
            l0 += __shfl_xor(l0, 16); l0 += __shfl_xor(l0, 32); l0 += bl0;
            l1 += __shfl_xor(l1, 16); l1 += __shfl_xor(l1, 32); l1 += bl1;

            float p0 = sigmoid_f(l0 - l1);
            float p1 = sigmoid_f(l1 - l0);
            float y0 = sqrtf(p0), y1 = sqrtf(p1);
            float ph0 = PI_F * l0 * rcp_fast(1.0f + fabsf(l0));
            float ph1 = PI_F * l1 * rcp_fast(1.0f + fabsf(l1));

            int bit = (int)((bmk[eh] >> s) & 1ull);
            bool is_even = (s & 1) == 0;
            float num   = is_even ? nu : nd;
            float lower = -16.0f + (float)(s >> 1);
            float occ   = (num < 16.0f) ? 1.0f : 0.0f;
            float unocc = (num > lower) ? 1.0f : 0.0f;
            if (s >= 16) {
                float m0 = y0 * unocc, m1 = y1 * occ;
                float nrm = fmaxf(sqrtf(m0 * m0 + m1 * m1), 1e-12f);
                float rn  = rcp_fast(nrm);
                y0 = m0 * rn; y1 = m1 * rn;
            }
            if (is_even) nu += (float)bit; else nd += (float)bit;
            amp *= bit ? y1 : y0;
            phs += bit ? ph1 : ph0;
        }
    }

    if (wv < 4 && q == 0) {
        int eg = ebg + eh;
        if (eg < nbatch) {
            float s, c;
            sincosf(phs, &s, &c);
            out[eg]          = amp * c;
            out[nbatch + eg] = amp * s;
        }
    }
}

extern "C" void kernel_launch(void* const* d_in, const int* in_sizes, int n_in,
                              void* d_out, int out_size, void* d_ws, size_t ws_size,
                              hipStream_t stream) {
    const int*   x     = (const int*)  d_in[0];
    const float* w_ih0 = (const float*)d_in[1];
    const float* w_hh0 = (const float*)d_in[2];
    const float* w_ih1 = (const float*)d_in[3];
    const float* w_hh1 = (const float*)d_in[4];
    const float* w_lin = (const float*)d_in[5];
    const float* b_lin = (const float*)d_in[6];
    float* out = (float*)d_out;
    _Float16* wsp = (_Float16*)d_ws;

    const int nbatch = in_sizes[0] / 64;

    prep_kernel<<<384, 256, 0, stream>>>(w_hh0, w_ih1, w_hh1, wsp);

    const int blocks = (nbatch + 63) / 64;
    rnn_wf_pipe<<<blocks, 512, 0, stream>>>(x, w_ih0, w_lin, b_lin, wsp, out, nbatch);
}

// Round 11
// 1539.459 us; speedup vs baseline: 1.1832x; 1.1758x over previous
//
#include <hip/hip_runtime.h>
#include <math.h>

#define PI_F 3.14159265358979323846f

typedef _Float16 half8 __attribute__((ext_vector_type(8)));
typedef _Float16 half4 __attribute__((ext_vector_type(4)));
typedef float f32x4 __attribute__((ext_vector_type(4)));

#define MFMA(a, b, c) __builtin_amdgcn_mfma_f32_16x16x32_f16(a, b, c, 0, 0, 0)
#define OFF_CAT 49152   // halfs: wcat starts after whh0 (3*128*128)

__device__ __forceinline__ float rcp_fast(float x) { return __builtin_amdgcn_rcpf(x); }
__device__ __forceinline__ float sigmoid_f(float x) {
    float e = __expf(-x);
    return rcp_fast(1.0f + e);
}
__device__ __forceinline__ float tanh_f(float x) {
    float ax = fabsf(x);
    float e  = __expf(-2.0f * ax);
    float t  = (1.0f - e) * rcp_fast(1.0f + e);
    return x >= 0.0f ? t : -t;
}

// Prep: f16 weights; concat [w_ih1|w_hh1] along K for layer 1.
__global__ void prep_kernel(const float* __restrict__ whh0,
                            const float* __restrict__ wih1,
                            const float* __restrict__ whh1,
                            _Float16* __restrict__ wsp) {
    int i = blockIdx.x * 256 + threadIdx.x;
    if (i < 49152) wsp[i] = (_Float16)whh0[i];
    if (i < 98304) {
        int n = i >> 8, k = i & 255;
        float v = (k < 128) ? wih1[(n << 7) + k] : whh1[(n << 7) + k - 128];
        wsp[OFF_CAT + i] = (_Float16)v;
    }
}

// 512 threads (8 waves), 64 elems/block, 1 block/CU, 2 waves/SIMD, 256 regs.
// Round-8 structure (best verified, 1654us): each wave owns 16 dims of BOTH
// layers; h state hi-only through LDS/MFMA; 2 barriers/tick
//     { A: h0(t) | bar | B: h1(t) | bar | head(t) || A(t+1) }
// Barrier-fusion triple-falsified (r3, r7, r9) -- sync structure is fixed.
//
// Round-10 isolation: of r10's two changes, "+a" AGPR pins were the
// regression (LLVM inserts v_accvgpr_read copies for MFMA operands); the f32
// register state was validated (absmax 1.16e-10 pass; WRITE_SIZE rise was a
// benign 14 B/thread once-per-setup spill, not per-tick). This round keeps
// ONLY the good half:
//
//   Own-dim h state in f32 REGISTERS (f32x4 h0s/h1s[4], statically indexed),
//   replacing the hi(LDS)+lo(reg) pair: deletes 16 ds_read_b64 + ~160 VALU
//   (cvt/add/lo-maintenance) per wave-tick and shortens the epilogue dep
//   chain (hprev in-reg, no lgkmcnt before the final fma). Recurrence is
//   exactly f32 (strictly more precise than hi+lo).
//
// Weight pins stay "+v" (proven r8 form). Gate pre-activations bit-identical
// to round-8 (same MFMA operands + order).
//
// h planes (64 elems) in MFMA-B-frag chunk order, double-buffered by parity:
//   plane[buf][(kc*4 + eb)*512 + (qd*16 + l4)*8 + j] = h[e=eb*16+l4][dim=32kc+8qd+j]

__global__ void __launch_bounds__(512, 2) rnn_wf_pipe(
    const int*   __restrict__ x,
    const float* __restrict__ w_ih0,
    const float* __restrict__ w_lin,
    const float* __restrict__ b_lin,
    const _Float16* __restrict__ wsp,
    float*       __restrict__ out,
    int nbatch)
{
    __shared__ _Float16 h0[2][8192], h1[2][8192];
    __shared__ float gi0T[2][3][128];          // [prev-bit][gate][dim]
    __shared__ float wlinT[256];               // w_lin flat
    __shared__ unsigned long long bmk[64];     // per-element bit mask

    const int t    = threadIdx.x;
    const int wv   = t >> 6;                   // 0..7 = dim-block (16 dims)
    const int l4   = t & 15;
    const int q    = (t >> 4) & 3;
    const int ebg  = blockIdx.x * 64;

    // ---- init LDS ----
    for (int i = t; i < 8192; i += 512) {      // 8192 ints = 2 bufs x 8192 halfs per array
        ((int*)h0)[i] = 0; ((int*)h1)[i] = 0;
    }
    for (int i = t; i < 768; i += 512) {
        int b = i / 384, rem = i - b * 384;
        ((float*)gi0T)[b * 384 + rem] = w_ih0[rem * 2 + b];
    }
    if (t < 256) wlinT[t] = w_lin[t];
    if (t < 256) {   // bit masks: thread t -> element t>>2, quarter t&3
        int el = t >> 2, qq = t & 3;
        int eg = ebg + el; if (eg >= nbatch) eg = nbatch - 1;
        const int* xr = x + (size_t)eg * 64 + qq * 16;
        unsigned long long m = 0ull;
#pragma unroll
        for (int i = 0; i < 16; ++i)
            m |= ((unsigned long long)((unsigned)(xr[i] + 1) >> 1)) << (qq * 16 + i);
        m |= __shfl_xor(m, 1);
        m |= __shfl_xor(m, 2);
        if (qq == 0) bmk[el] = m;
    }

    const int lo8 = ((q << 4) + l4) << 3;      // = lane*8 halfs: B-frag chunk offset
    const int d0  = wv * 16 + 4 * q;           // first of 4 dims this lane updates
    const int epb = (d0 >> 5) * 2048 + ((d0 >> 3) & 3) * 128 + l4 * 8 + (d0 & 7);

    // ---- register-resident weights ----
    half8 w0[3][4];                            // 48 regs
#pragma unroll
    for (int g = 0; g < 3; ++g)
#pragma unroll
        for (int kc = 0; kc < 4; ++kc)
            w0[g][kc] = *(const half8*)(wsp + (size_t)(g * 128 + 16 * wv + l4) * 128 + 32 * kc + 8 * q);
    half8 w1[3][8];                            // 96 regs
#pragma unroll
    for (int g = 0; g < 3; ++g)
#pragma unroll
        for (int kc = 0; kc < 8; ++kc)
            w1[g][kc] = *(const half8*)(wsp + OFF_CAT + (size_t)(g * 128 + 16 * wv + l4) * 256 + 32 * kc + 8 * q);

    // ---- own-dim h state in f32 registers (statically indexed) ----
    f32x4 h0s[4], h1s[4];
#pragma unroll
    for (int eb = 0; eb < 4; ++eb) {
        h0s[eb] = (f32x4){0.f, 0.f, 0.f, 0.f};
        h1s[eb] = (f32x4){0.f, 0.f, 0.f, 0.f};
    }

    // head state (waves 0-3, q-replicated)
    float amp = 1.0f, phs = 0.0f, nu = 0.0f, nd = 0.0f;
    float bl0 = 0.0f, bl1 = 0.0f;
    const int eh = (wv << 4) + l4;
    if (wv < 4) { bl0 = b_lin[0]; bl1 = b_lin[1]; }

    __syncthreads();

    for (int tick = 0; tick < 64; ++tick) {
        const int cur = tick & 1, prv = cur ^ 1;

        // pin weights: opaque loop-carried registers (no remat from memory)
#pragma unroll
        for (int g = 0; g < 3; ++g) {
#pragma unroll
            for (int kc = 0; kc < 4; ++kc) asm volatile("" : "+v"(w0[g][kc]));
#pragma unroll
            for (int kc = 0; kc < 8; ++kc) asm volatile("" : "+v"(w1[g][kc]));
        }

        // ---- Phase A: h0(tick) = GRU0(onehot(bit(tick-1)), h0(tick-1)) ----
#pragma unroll
        for (int eb = 0; eb < 4; ++eb) {
            f32x4 aR = {0,0,0,0}, aZ = {0,0,0,0}, aN = {0,0,0,0};
#pragma unroll
            for (int kc = 0; kc < 4; ++kc) {
                const int cb = (kc * 4 + eb) * 512 + lo8;
                half8 hh = *(const half8*)&h0[prv][cb];
                aR = MFMA(w0[0][kc], hh, aR);
                aZ = MFMA(w0[1][kc], hh, aZ);
                aN = MFMA(w0[2][kc], hh, aN);
            }
            const int e = eb * 16 + l4;
            f32x4 giR = {0,0,0,0}, giZ = {0,0,0,0}, giN = {0,0,0,0};
            if (tick > 0) {
                int pb = (int)((bmk[e] >> (tick - 1)) & 1ull);
                const float* gp = &gi0T[pb][0][0];
                giR = *(const f32x4*)(gp + d0);
                giZ = *(const f32x4*)(gp + 128 + d0);
                giN = *(const f32x4*)(gp + 256 + d0);
            }
            const int ep_ = epb + eb * 512;
            f32x4 hp = h0s[eb];
            f32x4 hnv;
            half4 nh;
#pragma unroll
            for (int r = 0; r < 4; ++r) {
                float rr = sigmoid_f(giR[r] + aR[r]);
                float zz = sigmoid_f(giZ[r] + aZ[r]);
                float nn = tanh_f(giN[r] + rr * aN[r]);
                float hn = (1.0f - zz) * nn + zz * hp[r];
                hnv[r] = hn;
                nh[r] = (_Float16)hn;
            }
            h0s[eb] = hnv;
            *(half4*)&h0[cur][ep_] = nh;
        }

        __syncthreads();

        // ---- Phase B: h1(tick) = GRU1(h0(tick), h1(tick-1)) ----
#pragma unroll
        for (int eb = 0; eb < 4; ++eb) {
            f32x4 aR = {0,0,0,0}, aZ = {0,0,0,0};
            f32x4 aNi = {0,0,0,0}, aNh = {0,0,0,0};
#pragma unroll
            for (int kc = 0; kc < 8; ++kc) {
                const int cb = ((kc & 3) * 4 + eb) * 512 + lo8;
                half8 hh;
                if (kc < 4) hh = *(const half8*)&h0[cur][cb];
                else        hh = *(const half8*)&h1[prv][cb];
                aR = MFMA(w1[0][kc], hh, aR);
                aZ = MFMA(w1[1][kc], hh, aZ);
                if (kc < 4) aNi = MFMA(w1[2][kc], hh, aNi);
                else        aNh = MFMA(w1[2][kc], hh, aNh);
            }
            const int ep_ = epb + eb * 512;
            f32x4 hp = h1s[eb];
            f32x4 hnv;
            half4 nh;
#pragma unroll
            for (int r = 0; r < 4; ++r) {
                float rr = sigmoid_f(aR[r]);
                float zz = sigmoid_f(aZ[r]);
                float nn = tanh_f(aNi[r] + rr * aNh[r]);
                float hn = (1.0f - zz) * nn + zz * hp[r];
                hnv[r] = hn;
                nh[r] = (_Float16)hn;
            }
            h1s[eb] = hnv;
            *(half4*)&h1[cur][ep_] = nh;
        }

        __syncthreads();

        // ---- head for step s = tick; h1(s) in buf cur.  Waves 0-3 only;
        //      waves 4-7 proceed straight into A(tick+1) (disjoint arrays).
        //      Lane-linear reads (conflict-free); xor-16/32 reduce. ----
        if (wv < 4) {
            const int s = tick;
            float l0 = 0.0f, l1 = 0.0f;
#pragma unroll
            for (int ks = 0; ks < 4; ++ks) {
                const int cb = (ks * 4 + wv) * 512 + lo8;
                half8 hh = *(const half8*)&h1[cur][cb];
                const float* wpl = &wlinT[32 * ks + 8 * q];
#pragma unroll
                for (int j = 0; j < 8; ++j) {
                    float hv = (float)hh[j];
                    l0 = fmaf(hv, wpl[j], l0);
                    l1 = fmaf(hv, wpl[128 + j], l1);
                }
            }
            l0 += __shfl_xor(l0, 16); l0 += __shfl_xor(l0, 32); l0 += bl0;
            l1 += __shfl_xor(l1, 16); l1 += __shfl_xor(l1, 32); l1 += bl1;

            float p0 = sigmoid_f(l0 - l1);
            float p1 = sigmoid_f(l1 - l0);
            float y0 = sqrtf(p0), y1 = sqrtf(p1);
            float ph0 = PI_F * l0 * rcp_fast(1.0f + fabsf(l0));
            float ph1 = PI_F * l1 * rcp_fast(1.0f + fabsf(l1));

            int bit = (int)((bmk[eh] >> s) & 1ull);
            bool is_even = (s & 1) == 0;
            float num   = is_even ? nu : nd;
            float lower = -16.0f + (float)(s >> 1);
            float occ   = (num < 16.0f) ? 1.0f : 0.0f;
            float unocc = (num > lower) ? 1.0f : 0.0f;
            if (s >= 16) {
                float m0 = y0 * unocc, m1 = y1 * occ;
                float nrm = fmaxf(sqrtf(m0 * m0 + m1 * m1), 1e-12f);
                float rn  = rcp_fast(nrm);
                y0 = m0 * rn; y1 = m1 * rn;
            }
            if (is_even) nu += (float)bit; else nd += (float)bit;
            amp *= bit ? y1 : y0;
            phs += bit ? ph1 : ph0;
        }
    }

    if (wv < 4 && q == 0) {
        int eg = ebg + eh;
        if (eg < nbatch) {
            float s, c;
            sincosf(phs, &s, &c);
            out[eg]          = amp * c;
            out[nbatch + eg] = amp * s;
        }
    }
}

extern "C" void kernel_launch(void* const* d_in, const int* in_sizes, int n_in,
                              void* d_out, int out_size, void* d_ws, size_t ws_size,
                              hipStream_t stream) {
    const int*   x     = (const int*)  d_in[0];
    const float* w_ih0 = (const float*)d_in[1];
    const float* w_hh0 = (const float*)d_in[2];
    const float* w_ih1 = (const float*)d_in[3];
    const float* w_hh1 = (const float*)d_in[4];
    const float* w_lin = (const float*)d_in[5];
    const float* b_lin = (const float*)d_in[6];
    float* out = (float*)d_out;
    _Float16* wsp = (_Float16*)d_ws;

    const int nbatch = in_sizes[0] / 64;

    prep_kernel<<<384, 256, 0, stream>>>(w_hh0, w_ih1, w_hh1, wsp);

    const int blocks = (nbatch + 63) / 64;
    rnn_wf_pipe<<<blocks, 512, 0, stream>>>(x, w_ih0, w_lin, b_lin, wsp, out, nbatch);
}